// Round 4
// baseline (331.088 us; speedup 1.0000x reference)
//
#include <hip/hip_runtime.h>
#include <hip/hip_bf16.h>

// FrameWiseCrossAttention: kv_len==1 => softmax==1 => out = broadcast(y),
// y = (c @ Wv^T + bv) @ Wo^T + bo. x/Wq/Wk/bq/bk are mathematically unused.
// B=2, T=16, tpf=1560, N=24960, DIM=1024. M = B*T = 32 rows.
//
// Two dispatches:
//   1) gemm_thin:  v[32,1024] = c @ Wv^T + bv
//   2) gemm_bcast: each block computes a 32-column slice of y[bt,:] and
//      broadcasts it to all 1560 token rows (fuses GEMM2 + broadcast, no y
//      round-trip, no third launch).

#define DIM    1024
#define K4     (DIM / 4)    // 256 float4 per row
#define MROWS  32           // B*T
#define TPF    1560
#define CC     32           // columns per gemm_bcast block

typedef float fvec4 __attribute__((ext_vector_type(4)));

// C[32,1024] = A[32,1024] @ W[1024,1024]^T + bias.
// 512 blocks x 256 threads. Block b owns columns 2b, 2b+1; wave w owns rows
// 8w..8w+7; K lane-sliced so every load is a coalesced 1KB dwordx4.
__global__ __launch_bounds__(256) void gemm_thin(const float* __restrict__ A,
                                                 const float* __restrict__ W,
                                                 const float* __restrict__ bias,
                                                 float* __restrict__ C) {
    const int wave = threadIdx.x >> 6;
    const int lane = threadIdx.x & 63;
    const int j0   = blockIdx.x * 2;
    const int r0   = wave * 8;

    const fvec4* __restrict__ A4 = (const fvec4*)A;
    const fvec4* __restrict__ W0 = (const fvec4*)(W + (size_t)j0 * DIM);
    const fvec4* __restrict__ W1 = (const fvec4*)(W + (size_t)(j0 + 1) * DIM);

    fvec4 wa[4], wb[4];
#pragma unroll
    for (int t = 0; t < 4; ++t) {
        wa[t] = W0[t * 64 + lane];
        wb[t] = W1[t * 64 + lane];
    }

    float accA[8], accB[8];
#pragma unroll
    for (int r = 0; r < 8; ++r) { accA[r] = 0.f; accB[r] = 0.f; }

#pragma unroll
    for (int r = 0; r < 8; ++r) {
        const fvec4* __restrict__ Ar = A4 + (size_t)(r0 + r) * K4;
#pragma unroll
        for (int t = 0; t < 4; ++t) {
            fvec4 a = Ar[t * 64 + lane];
            accA[r] += a.x * wa[t].x + a.y * wa[t].y + a.z * wa[t].z + a.w * wa[t].w;
            accB[r] += a.x * wb[t].x + a.y * wb[t].y + a.z * wb[t].z + a.w * wb[t].w;
        }
    }

#pragma unroll
    for (int r = 0; r < 8; ++r) {
        float va = accA[r], vb = accB[r];
#pragma unroll
        for (int off = 32; off > 0; off >>= 1) {
            va += __shfl_down(va, off, 64);
            vb += __shfl_down(vb, off, 64);
        }
        accA[r] = va; accB[r] = vb;
    }

    if (lane == 0) {
        const float b0 = bias[j0], b1 = bias[j0 + 1];
#pragma unroll
        for (int r = 0; r < 8; ++r) {
            C[(size_t)(r0 + r) * DIM + j0]     = accA[r] + b0;
            C[(size_t)(r0 + r) * DIM + j0 + 1] = accB[r] + b1;
        }
    }
}

// Fused y-slice + broadcast. grid = 32 bt * 32 chunks = 1024 blocks.
// Step A: block computes y[bt, j0:j0+32] (wave w does 8 columns, K
// lane-sliced, shuffle-reduced, result in LDS).
// Step B: all 256 threads stream the 128B slice to 1560 token rows.
__global__ __launch_bounds__(256) void gemm_bcast(const float* __restrict__ v,
                                                  const float* __restrict__ Wo,
                                                  const float* __restrict__ bo,
                                                  float* __restrict__ out) {
    const int bt   = blockIdx.x >> 5;
    const int j0   = (blockIdx.x & 31) * CC;
    const int wave = threadIdx.x >> 6;
    const int lane = threadIdx.x & 63;

    __shared__ float yS[CC];

    const fvec4* __restrict__ V4 = (const fvec4*)(v + (size_t)bt * DIM);
    fvec4 vr[4];
#pragma unroll
    for (int t = 0; t < 4; ++t) vr[t] = V4[t * 64 + lane];

#pragma unroll
    for (int cc = 0; cc < 8; ++cc) {
        const int j = j0 + wave * 8 + cc;
        const fvec4* __restrict__ Wr = (const fvec4*)(Wo + (size_t)j * DIM);
        float acc = 0.f;
#pragma unroll
        for (int t = 0; t < 4; ++t) {
            fvec4 w = Wr[t * 64 + lane];
            acc += w.x * vr[t].x + w.y * vr[t].y + w.z * vr[t].z + w.w * vr[t].w;
        }
#pragma unroll
        for (int off = 32; off > 0; off >>= 1) acc += __shfl_down(acc, off, 64);
        if (lane == 0) yS[j - j0] = acc + bo[j];
    }
    __syncthreads();

    // Step B: thread t owns float4 c4 = t&7 of the slice, rows p = (t>>3) + 32*i.
    const int c4 = threadIdx.x & 7;
    const int r0 = threadIdx.x >> 3;
    const fvec4 val = ((const fvec4*)yS)[c4];

    fvec4* obase = (fvec4*)(out + (size_t)bt * TPF * DIM + j0);
    for (int p = r0; p < TPF; p += 32) {
        obase[(size_t)p * K4 + c4] = val;   // 128B-dense segments, coalesced
    }
}

extern "C" void kernel_launch(void* const* d_in, const int* in_sizes, int n_in,
                              void* d_out, int out_size, void* d_ws, size_t ws_size,
                              hipStream_t stream) {
    // inputs: 0=x 1=c 2=Wq 3=bq 4=Wk 5=bk 6=Wv 7=bv 8=Wo 9=bo
    const float* c  = (const float*)d_in[1];
    const float* Wv = (const float*)d_in[6];
    const float* bv = (const float*)d_in[7];
    const float* Wo = (const float*)d_in[8];
    const float* bo = (const float*)d_in[9];
    float* out = (float*)d_out;

    float* v = (float*)d_ws;                  // [32,1024]

    gemm_thin<<<DIM / 2, 256, 0, stream>>>(c, Wv, bv, v);
    gemm_bcast<<<MROWS * (DIM / CC), 256, 0, stream>>>(v, Wo, bo, out);
}

// Round 5
// 330.731 us; speedup vs baseline: 1.0011x; 1.0011x over previous
//
#include <hip/hip_runtime.h>
#include <hip/hip_bf16.h>

// FrameWiseCrossAttention: kv_len==1 => softmax==1 => out = broadcast(y),
// y = (c @ Wv^T + bv) @ Wo^T + bo. x/Wq/Wk/bq/bk are mathematically unused.
// B=2, T=16, tpf=1560, N=24960, DIM=1024. M = B*T = 32 rows.
//
// Structural floor: 204.5 MB output write ≈ 31 µs at the demonstrated
// 6.6 TB/s fill rate; gemms ~4 µs. Most of dur_us is harness reset traffic
// (818 MB poison fill + 204 MB out poison + 204 MB x restore per iteration).

#define DIM    1024
#define K4     (DIM / 4)    // 256 float4 per row
#define MROWS  32           // B*T
#define TPF    1560
#define CC     32           // columns per gemm_bcast block

typedef float fvec4 __attribute__((ext_vector_type(4)));

// C[32,1024] = A[32,1024] @ W[1024,1024]^T + bias.
// 512 blocks x 256 threads. Block b owns columns 2b, 2b+1; wave w owns rows
// 8w..8w+7; K lane-sliced so every load is a coalesced 1KB dwordx4.
__global__ __launch_bounds__(256) void gemm_thin(const float* __restrict__ A,
                                                 const float* __restrict__ W,
                                                 const float* __restrict__ bias,
                                                 float* __restrict__ C) {
    const int wave = threadIdx.x >> 6;
    const int lane = threadIdx.x & 63;
    const int j0   = blockIdx.x * 2;
    const int r0   = wave * 8;

    const fvec4* __restrict__ A4 = (const fvec4*)A;
    const fvec4* __restrict__ W0 = (const fvec4*)(W + (size_t)j0 * DIM);
    const fvec4* __restrict__ W1 = (const fvec4*)(W + (size_t)(j0 + 1) * DIM);

    fvec4 wa[4], wb[4];
#pragma unroll
    for (int t = 0; t < 4; ++t) {
        wa[t] = W0[t * 64 + lane];
        wb[t] = W1[t * 64 + lane];
    }

    float accA[8], accB[8];
#pragma unroll
    for (int r = 0; r < 8; ++r) { accA[r] = 0.f; accB[r] = 0.f; }

#pragma unroll
    for (int r = 0; r < 8; ++r) {
        const fvec4* __restrict__ Ar = A4 + (size_t)(r0 + r) * K4;
#pragma unroll
        for (int t = 0; t < 4; ++t) {
            fvec4 a = Ar[t * 64 + lane];
            accA[r] += a.x * wa[t].x + a.y * wa[t].y + a.z * wa[t].z + a.w * wa[t].w;
            accB[r] += a.x * wb[t].x + a.y * wb[t].y + a.z * wb[t].z + a.w * wb[t].w;
        }
    }

#pragma unroll
    for (int r = 0; r < 8; ++r) {
        float va = accA[r], vb = accB[r];
#pragma unroll
        for (int off = 32; off > 0; off >>= 1) {
            va += __shfl_down(va, off, 64);
            vb += __shfl_down(vb, off, 64);
        }
        accA[r] = va; accB[r] = vb;
    }

    if (lane == 0) {
        const float b0 = bias[j0], b1 = bias[j0 + 1];
#pragma unroll
        for (int r = 0; r < 8; ++r) {
            C[(size_t)(r0 + r) * DIM + j0]     = accA[r] + b0;
            C[(size_t)(r0 + r) * DIM + j0 + 1] = accB[r] + b1;
        }
    }
}

// Fused y-slice + broadcast. grid = 32 bt * 32 chunks = 1024 blocks (4/CU).
// Step A: block computes y[bt, j0:j0+32] (wave w does 8 columns, K
// lane-sliced, shuffle-reduced, result in LDS).
// Step B: all 256 threads stream the 128B slice to 1560 token rows with
// nontemporal stores (pure streaming; keep L2 for weights/v).
__global__ __launch_bounds__(256) void gemm_bcast(const float* __restrict__ v,
                                                  const float* __restrict__ Wo,
                                                  const float* __restrict__ bo,
                                                  float* __restrict__ out) {
    const int bt   = blockIdx.x >> 5;
    const int j0   = (blockIdx.x & 31) * CC;
    const int wave = threadIdx.x >> 6;
    const int lane = threadIdx.x & 63;

    __shared__ float yS[CC];

    const fvec4* __restrict__ V4 = (const fvec4*)(v + (size_t)bt * DIM);
    fvec4 vr[4];
#pragma unroll
    for (int t = 0; t < 4; ++t) vr[t] = V4[t * 64 + lane];

#pragma unroll
    for (int cc = 0; cc < 8; ++cc) {
        const int j = j0 + wave * 8 + cc;
        const fvec4* __restrict__ Wr = (const fvec4*)(Wo + (size_t)j * DIM);
        float acc = 0.f;
#pragma unroll
        for (int t = 0; t < 4; ++t) {
            fvec4 w = Wr[t * 64 + lane];
            acc += w.x * vr[t].x + w.y * vr[t].y + w.z * vr[t].z + w.w * vr[t].w;
        }
#pragma unroll
        for (int off = 32; off > 0; off >>= 1) acc += __shfl_down(acc, off, 64);
        if (lane == 0) yS[j - j0] = acc + bo[j];
    }
    __syncthreads();

    // Step B: thread t owns float4 c4 = t&7 of the slice, rows p = (t>>3) + 32*i.
    const int c4 = threadIdx.x & 7;
    const int r0 = threadIdx.x >> 3;
    const fvec4 val = ((const fvec4*)yS)[c4];

    fvec4* obase = (fvec4*)(out + (size_t)bt * TPF * DIM + j0);
    // 1560/32 = 48.75 -> 48 full steps for r0<24? No: p = r0 + 32*i, i in [0,48];
    // last step valid iff r0 < 1560 - 48*32 = 24.
#pragma unroll 4
    for (int i = 0; i < 48; ++i) {
        __builtin_nontemporal_store(val, &obase[((size_t)(r0 + 32 * i)) * K4 + c4]);
    }
    if (r0 < TPF - 48 * 32) {
        __builtin_nontemporal_store(val, &obase[((size_t)(r0 + 48 * 32)) * K4 + c4]);
    }
}

extern "C" void kernel_launch(void* const* d_in, const int* in_sizes, int n_in,
                              void* d_out, int out_size, void* d_ws, size_t ws_size,
                              hipStream_t stream) {
    // inputs: 0=x 1=c 2=Wq 3=bq 4=Wk 5=bk 6=Wv 7=bv 8=Wo 9=bo
    const float* c  = (const float*)d_in[1];
    const float* Wv = (const float*)d_in[6];
    const float* bv = (const float*)d_in[7];
    const float* Wo = (const float*)d_in[8];
    const float* bo = (const float*)d_in[9];
    float* out = (float*)d_out;

    float* v = (float*)d_ws;                  // [32,1024]

    gemm_thin<<<DIM / 2, 256, 0, stream>>>(c, Wv, bv, v);
    gemm_bcast<<<MROWS * (DIM / CC), 256, 0, stream>>>(v, Wo, bo, out);
}